// Round 8
// baseline (193.225 us; speedup 1.0000x reference)
//
#include <hip/hip_runtime.h>

#define BB 256
#define LL 2048
#define HH 64
#define TT 64            // chunk length along L
#define SS 68            // padded LDS row stride (floats)
#define NCH (LL / TT)    // 32 chunks
#define NTOT (BB * LL * 2)

typedef __attribute__((ext_vector_type(8))) short bf16x8;
typedef __attribute__((ext_vector_type(4))) float f32x4;

__device__ __forceinline__ float rcp_(float x)  { return __builtin_amdgcn_rcpf(x); }

// RNE fp32->bf16 (weights only, outside hot loop)
__device__ __forceinline__ short f2bf_rne(float f) {
    union { float f; unsigned u; } v; v.f = f;
    unsigned r = v.u + 0x7fff + ((v.u >> 16) & 1);
    return (short)(r >> 16);
}

// pack hi16(f_hi):hi16(f_lo) into one dword with a single v_perm_b32
__device__ __forceinline__ unsigned perm_hi16(float f_hi, float f_lo) {
    union { float f; unsigned u; } a, b;
    a.f = f_hi; b.f = f_lo;
    return __builtin_amdgcn_perm(a.u, b.u, 0x07060302u);
}

// DPP row_shr:D with zero bound: lane i receives lane i-D within its 16-lane row.
template<int D>
__device__ __forceinline__ float rshr(float x) {
    union { float f; int i; } u, r;
    u.f = x;
    r.i = __builtin_amdgcn_update_dpp(0, u.i, 0x110 | D, 0xF, 0xF, true);
    return r.f;
}

// broadcast lane (group8 | 7) within each 8-lane group: ds_swizzle bit-mode,
// src = (lane & 0x18) | 7  ->  offset = (7<<5)|0x18 = 0xF8 (per 32-lane half).
__device__ __forceinline__ float bcast7(float x) {
    union { float f; int i; } u, r;
    u.f = x;
    r.i = __builtin_amdgcn_ds_swizzle(u.i, 0x00F8);
    return r.f;
}

// Layer-0 gates (Bernoulli bit-LUT) + 64-step chunk scan split over 8 waves:
// each lane owns 8 local steps (seg = lane&7); guarded row_shr DPP scan over
// segments. ai/bi cached in 16 VGPRs (headroom exists at 64 live regs; the
// recompute variant costs 32 extra select ops per lane per chunk).
__device__ __forceinline__ void p1_scan(const unsigned* __restrict__ bw, int c,
                                        float a0v, float b0v, float a1v, float b1v,
                                        int seg, int col0,
                                        float& carry, float* sh)
{
    const unsigned bits = (bw[c * 2 + (seg >> 2)] >> ((seg & 3) << 3)) & 0xffu;
    float ai[8], bi[8];
    float A = 1.0f, Bv = 0.0f;
    #pragma unroll
    for (int i = 0; i < 8; ++i) {
        const bool on = (bits >> i) & 1u;
        ai[i] = on ? a1v : a0v;
        bi[i] = on ? b1v : b0v;
        A  = A * ai[i];
        Bv = fmaf(Bv, ai[i], bi[i]);
    }
    // inclusive Hillis-Steele over 8 segments (strides 1,2,4)
    {
        const float Au = rshr<1>(A), Bu = rshr<1>(Bv);
        if (seg >= 1) { const float Ac = A; A = Au * Ac; Bv = fmaf(Bu, Ac, Bv); }
    }
    {
        const float Au = rshr<2>(A), Bu = rshr<2>(Bv);
        if (seg >= 2) { const float Ac = A; A = Au * Ac; Bv = fmaf(Bu, Ac, Bv); }
    }
    {
        const float Au = rshr<4>(A), Bu = rshr<4>(Bv);
        if (seg >= 4) { const float Ac = A; A = Au * Ac; Bv = fmaf(Bu, Ac, Bv); }
    }
    // exclusive transform for this segment's incoming state
    float Ae = rshr<1>(A), Be = rshr<1>(Bv);
    if (seg == 0) { Ae = 1.0f; Be = 0.0f; }
    float cc = fmaf(Ae, carry, Be);
    #pragma unroll
    for (int i = 0; i < 8; ++i) {
        cc = fmaf(ai[i], cc, bi[i]);
        sh[(seg * 8 + i) * SS + col0] = cc;
    }
    carry = bcast7(cc);   // seg==7 lane of this h-group holds chunk-final state
}

// 8 waves = 4 t-waves x 2 h-halves (in-block H-split), r5 skeleton.
// This rev: issue-slot trims (ai/bi cache, uniform tw/hw via readfirstlane,
// hoisted A-tile loads, P1 moved ahead of G2). Gate kept on the proven
// __expf path (round-6's __builtin_amdgcn_exp2f is the prime suspect for
// the back-to-back container failures: unverified builtin -> compile crash).
__global__ void __launch_bounds__(512)
__attribute__((amdgpu_waves_per_eu(4, 4)))
gru_fused(const float* __restrict__ x, const int* __restrict__ p,
               const float* __restrict__ w1z0, const float* __restrict__ b1z0,
               const float* __restrict__ w1h0, const float* __restrict__ b1h0,
               const float* __restrict__ w1z1, const float* __restrict__ b1z1,
               const float* __restrict__ w1h1, const float* __restrict__ b1h1,
               const float* __restrict__ w1o,  const float* __restrict__ b1o,
               const float* __restrict__ w2z0, const float* __restrict__ b2z0,
               const float* __restrict__ w2h0, const float* __restrict__ b2h0,
               const float* __restrict__ w2z1, const float* __restrict__ b2z1,
               const float* __restrict__ w2h1, const float* __restrict__ b2h1,
               const float* __restrict__ w2o,  const float* __restrict__ b2o,
               float* __restrict__ out, float* __restrict__ ws)
{
    const int  b  = blockIdx.x;
    const bool pm = (blockIdx.y != 0);

    const float* wz0 = pm ? w2z0 : w1z0;
    const float* bz0 = pm ? b2z0 : b1z0;
    const float* wh0 = pm ? w2h0 : w1h0;
    const float* bh0 = pm ? b2h0 : b1h0;
    const float* wz1 = pm ? w2z1 : w1z1;
    const float* bz1 = pm ? b2z1 : b1z1;
    const float* wh1 = pm ? w2h1 : w1h1;
    const float* bh1 = pm ? b2h1 : b1h1;
    const float* wo  = pm ? w2o  : w1o;
    const float* bov = pm ? b2o  : b1o;

    const int tid   = threadIdx.x;
    const int lane  = tid & 63;
    const int tg    = tid >> 6;          // wave id (8)
    const int tgu   = __builtin_amdgcn_readfirstlane(tg);   // provably uniform
    const int twu   = tgu & 3;           // t sub-block wave (uniform)
    const int hwu   = tgu >> 2;          // h-half (uniform)
    const int q     = lane >> 4;         // MFMA quad (t sub-block)
    const int n     = lane & 15;         // MFMA col (h low bits)
    const int seg   = lane & 7;          // P1 segment (8 per h)
    const int hidx  = (tgu << 3) | (lane >> 3);   // P1 h channel (0..63)

    __shared__ __align__(16) float s_h[2 * TT * SS];   // double-buffered h0 (34.8 KB)
    __shared__ unsigned long long s_xb[LL / 64];       // bit-packed (permuted) x row
    __shared__ float2 s_w[2][2][4][32];                // [buf][hw][tw][ht*16+n]
    __shared__ float s_o[2][4][16];                    // [buf][tw][q*4+r] hw1 partials
    __shared__ float s_red[16];

    const float* xrow = x + (size_t)b * LL;

    // ---- stage x row as BITS (ballot-packed; pm branch gathers once here) ----
    #pragma unroll
    for (int g = 0; g < 4; ++g) {
        const int idx = g * 512 + tid;
        const int src = pm ? p[idx] : idx;
        const unsigned long long m = __ballot(xrow[src] != 0.0f);
        if (lane == 0) s_xb[g * 8 + tgu] = m;
    }
    const unsigned* bw = (const unsigned*)s_xb;

    // ---- layer-0 LUT per hidx (x is bernoulli {0,1}) ----
    const float z0v = rcp_(1.0f + __expf(-bz0[hidx]));
    const float z1v = rcp_(1.0f + __expf(-(wz0[hidx] + bz0[hidx])));
    const float a0v = 1.0f - z0v, b0v = z0v * bh0[hidx];
    const float a1v = 1.0f - z1v, b1v = z1v * (wh0[hidx] + bh0[hidx]);

    // ---- layer-1 biases + output weights for THIS h-half ----
    float rbz1[2], rbh1[2], rwo4[2];
    #pragma unroll
    for (int ht = 0; ht < 2; ++ht) {
        const int h = hwu * 32 + ht * 16 + n;
        rbz1[ht] = bz1[h];
        rbh1[ht] = bh1[h];
        rwo4[ht] = wo[h];
    }
    const float bo = bov[0];   // added once, by hw0 at combine time

    // ---- layer-1 weight B-fragments (this half), RNE hi only ----
    bf16x8 wfz[2][2], wfh[2][2];
    for (int ks = 0; ks < 2; ++ks) {
        for (int ht = 0; ht < 2; ++ht) {
            #pragma unroll
            for (int j = 0; j < 8; ++j) {
                const int kk = ks * 32 + q * 8 + j;
                const int h  = hwu * 32 + ht * 16 + n;
                wfz[ks][ht][j] = f2bf_rne(wz1[kk * HH + h]);
                wfh[ks][ht][j] = f2bf_rne(wh1[kk * HH + h]);
            }
        }
    }

    float carry0 = 0.0f;
    float carry1[2] = {0.0f, 0.0f};    // per ht (h = hw*32 + ht*16 + n)
    f32x4 ga[2], gb[2];                // layer-1 gates (a,b), chunk-persistent
    float Aqe[2], Bqe[2];              // exclusive-q transforms, chunk-persistent
    float pvo[4] = {0, 0, 0, 0};       // hw0's deferred projection partials
    float lsum = 0.0f, lsum2 = 0.0f;
    float* outp = out + (pm ? 1 : 0);
    const int t0 = twu * 16;
    const int col0 = hidx ^ (seg << 2);           // s_h col swizzle (write side)
    const int sswz = (twu * 2 + (n >> 3)) << 2;   // read-side un-swizzle

    // G2: deferred combine of chunk cm-1 (hw1's partial arrived via s_o, synced),
    // then apply layer-1 scan for chunk cm + half projection.
    auto g2_step = [&](int cm) {
        if (cm > 0 && hwu == 0 && n == 15) {
            #pragma unroll
            for (int r = 0; r < 4; ++r) {
                const float v = pvo[r] + s_o[(cm - 1) & 1][twu][q * 4 + r] + bo;
                outp[((size_t)b * LL + (cm - 1) * TT + t0 + q * 4 + r) * 2] = v;
                lsum += v;
                lsum2 = fmaf(v, v, lsum2);
            }
        }
        const int buf = cm & 1;
        float Acm[2] = {1, 1}, Bcm[2] = {0, 0};
        float Ap[2], Bp[2];
        #pragma unroll
        for (int w = 0; w < 4; ++w) {
            #pragma unroll
            for (int ht = 0; ht < 2; ++ht) {
                if (w == twu) { Ap[ht] = Acm[ht]; Bp[ht] = Bcm[ht]; }  // uniform branch
                const float2 ab = s_w[buf][hwu][w][ht * 16 + n];
                Bcm[ht] = fmaf(ab.x, Bcm[ht], ab.y);
                Acm[ht] *= ab.x;
            }
        }
        float vo[4] = {0, 0, 0, 0};
        #pragma unroll
        for (int ht = 0; ht < 2; ++ht) {
            float cc = fmaf(Aqe[ht], fmaf(Ap[ht], carry1[ht], Bp[ht]), Bqe[ht]);
            #pragma unroll
            for (int r = 0; r < 4; ++r) {
                cc = fmaf(ga[ht][r], cc, gb[ht][r]);
                vo[r] = fmaf(cc, rwo4[ht], vo[r]);
            }
            carry1[ht] = fmaf(Acm[ht], carry1[ht], Bcm[ht]);
        }
        // shift-reduce over n (16-lane rows): lane n==15 gets the half-sum
        #pragma unroll
        for (int r = 0; r < 4; ++r) {
            vo[r] += rshr<1>(vo[r]);
            vo[r] += rshr<2>(vo[r]);
            vo[r] += rshr<4>(vo[r]);
            vo[r] += rshr<8>(vo[r]);
        }
        if (n == 15) {
            if (hwu) {
                #pragma unroll
                for (int r = 0; r < 4; ++r) s_o[buf][twu][q * 4 + r] = vo[r];
            } else {
                #pragma unroll
                for (int r = 0; r < 4; ++r) pvo[r] = vo[r];
            }
        }
    };

    __syncthreads();   // s_xb staged

    // ---- prologue: P1(0) -> s_h buf 0 ----
    p1_scan(bw, 0, a0v, b0v, a1v, b1v, seg, col0, carry0, s_h);
    __syncthreads();

    for (int c = 0; c < NCH; ++c) {
        const int cp1 = c + 1;

        // ---- hoist G1(c)'s A-tile loads: latency hides under P1 + G2 ----
        const float* shR = s_h + (c & 1) * (TT * SS);
        const float* rowp = &shR[(t0 + n) * SS];
        float4 L[4];
        #pragma unroll
        for (int ks = 0; ks < 2; ++ks) {
            const int base = ks * 32 + q * 8;
            L[2 * ks + 0] = *(const float4*)(rowp + (base ^ sswz));
            L[2 * ks + 1] = *(const float4*)(rowp + ((base + 4) ^ sswz));
        }

        // ---- P1(c+1) -> other s_h buffer (serial DPP chain, overlaps G2) ----
        if (cp1 < NCH)
            p1_scan(bw, cp1, a0v, b0v, a1v, b1v, seg, col0, carry0,
                    s_h + (cp1 & 1) * (TT * SS));

        // ---- G2(c-1): uses previous chunk's gates (still in registers) ----
        if (c > 0) g2_step(c - 1);

        // ---- G1(c): repack + MFMA + gates + per-wave scan transforms ----
        {
            #pragma unroll
            for (int ht = 0; ht < 2; ++ht) {
                ga[ht] = (f32x4){rbz1[ht], rbz1[ht], rbz1[ht], rbz1[ht]};
                gb[ht] = (f32x4){rbh1[ht], rbh1[ht], rbh1[ht], rbh1[ht]};
            }
            #pragma unroll
            for (int ks = 0; ks < 2; ++ks) {
                const float4 av0 = L[2 * ks + 0];
                const float4 av1 = L[2 * ks + 1];
                float af[8] = {av0.x, av0.y, av0.z, av0.w, av1.x, av1.y, av1.z, av1.w};
                // hi16 pack via v_perm; exact remainder -> lo bf16
                union { bf16x8 v; unsigned d[4]; } ahi, alo;
                float rem[8];
                #pragma unroll
                for (int j = 0; j < 8; ++j) {
                    union { float f; unsigned u; } uf; uf.f = af[j];
                    union { unsigned u; float f; } hf; hf.u = uf.u & 0xffff0000u;
                    rem[j] = af[j] - hf.f;                     // exact
                }
                #pragma unroll
                for (int k = 0; k < 4; ++k) {
                    ahi.d[k] = perm_hi16(af[2 * k + 1], af[2 * k]);
                    alo.d[k] = perm_hi16(rem[2 * k + 1], rem[2 * k]);
                }
                #pragma unroll
                for (int ht = 0; ht < 2; ++ht) {
                    ga[ht] = __builtin_amdgcn_mfma_f32_16x16x32_bf16(ahi.v, wfz[ks][ht], ga[ht], 0, 0, 0);
                    ga[ht] = __builtin_amdgcn_mfma_f32_16x16x32_bf16(alo.v, wfz[ks][ht], ga[ht], 0, 0, 0);
                    gb[ht] = __builtin_amdgcn_mfma_f32_16x16x32_bf16(ahi.v, wfh[ks][ht], gb[ht], 0, 0, 0);
                    gb[ht] = __builtin_amdgcn_mfma_f32_16x16x32_bf16(alo.v, wfh[ks][ht], gb[ht], 0, 0, 0);
                }
            }
            // gates in place: a = 1-sigmoid(v) = rcp(1+exp(v)); b = htl - a*htl
            #pragma unroll
            for (int ht = 0; ht < 2; ++ht) {
                #pragma unroll
                for (int r = 0; r < 4; ++r) {
                    const float v   = ga[ht][r];
                    const float a   = rcp_(1.0f + __expf(v));
                    const float htl = gb[ht][r];
                    ga[ht][r] = a;
                    gb[ht][r] = fmaf(-a, htl, htl);
                }
            }
            // compose own 4 r-steps per ht
            float Aq[2], Bq[2];
            #pragma unroll
            for (int ht = 0; ht < 2; ++ht) {
                float A = 1.0f, B = 0.0f;
                #pragma unroll
                for (int r = 0; r < 4; ++r) {
                    B = fmaf(ga[ht][r], B, gb[ht][r]);
                    A = A * ga[ht][r];
                }
                Aq[ht] = A; Bq[ht] = B;
            }
            // inclusive Hillis-Steele over q (strides 16, 32 lanes)
            #pragma unroll
            for (int ht = 0; ht < 2; ++ht) {
                const float Au = __shfl_up(Aq[ht], 16), Bu = __shfl_up(Bq[ht], 16);
                if (q >= 1) { const float Ac = Aq[ht]; Aq[ht] = Ac * Au; Bq[ht] = fmaf(Ac, Bu, Bq[ht]); }
            }
            #pragma unroll
            for (int ht = 0; ht < 2; ++ht) {
                const float Au = __shfl_up(Aq[ht], 32), Bu = __shfl_up(Bq[ht], 32);
                if (q >= 2) { const float Ac = Aq[ht]; Aq[ht] = Ac * Au; Bq[ht] = fmaf(Ac, Bu, Bq[ht]); }
            }
            // exclusive-q transforms (persist to G2)
            #pragma unroll
            for (int ht = 0; ht < 2; ++ht) {
                const float Ae = __shfl_up(Aq[ht], 16), Be = __shfl_up(Bq[ht], 16);
                Aqe[ht] = (q == 0) ? 1.0f : Ae;
                Bqe[ht] = (q == 0) ? 0.0f : Be;
            }
            // q==3 lanes publish the wave-block inclusive transform
            if (q == 3) {
                #pragma unroll
                for (int ht = 0; ht < 2; ++ht)
                    s_w[c & 1][hwu][twu][ht * 16 + n] = make_float2(Aq[ht], Bq[ht]);
            }
        }

        __syncthreads();
    }

    // ---- G2 for the last chunk, then final deferred combine ----
    g2_step(NCH - 1);
    __syncthreads();
    if (hwu == 0 && n == 15) {
        #pragma unroll
        for (int r = 0; r < 4; ++r) {
            const float v = pvo[r] + s_o[(NCH - 1) & 1][twu][q * 4 + r] + bo;
            outp[((size_t)b * LL + (NCH - 1) * TT + t0 + q * 4 + r) * 2] = v;
            lsum += v;
            lsum2 = fmaf(v, v, lsum2);
        }
    }

    // ---- block partial (sum, sumsq) -> ws slots (plain stores) ----
    #pragma unroll
    for (int o = 32; o; o >>= 1) {
        lsum  += __shfl_down(lsum, o);
        lsum2 += __shfl_down(lsum2, o);
    }
    if (lane == 0) { s_red[tgu] = lsum; s_red[8 + tgu] = lsum2; }
    __syncthreads();
    if (tid == 0) {
        float s = 0.0f, s2 = 0.0f;
        #pragma unroll
        for (int i = 0; i < 8; ++i) { s += s_red[i]; s2 += s_red[8 + i]; }
        const int gb2 = b * 2 + (pm ? 1 : 0);
        ws[2 * gb2]     = s;
        ws[2 * gb2 + 1] = s2;
    }
}

// Fold the 512 block-partials (redundantly per block), normalize in-place.
__global__ void normalize_k(float* __restrict__ out, const float* __restrict__ ws)
{
    __shared__ float s_red[8];
    float s = 0.0f, s2 = 0.0f;
    for (int i = threadIdx.x; i < 2 * BB; i += 256) {
        s  += ws[2 * i];
        s2 += ws[2 * i + 1];
    }
    #pragma unroll
    for (int o = 32; o; o >>= 1) {
        s  += __shfl_down(s, o);
        s2 += __shfl_down(s2, o);
    }
    const int wid = threadIdx.x >> 6;
    if ((threadIdx.x & 63) == 0) { s_red[wid] = s; s_red[4 + wid] = s2; }
    __syncthreads();
    const float tot  = s_red[0] + s_red[1] + s_red[2] + s_red[3];
    const float tot2 = s_red[4] + s_red[5] + s_red[6] + s_red[7];
    const float N    = (float)NTOT;
    const float mean = tot / N;
    const float var  = (tot2 - N * mean * mean) / (N - 1.0f);
    const float inv  = rsqrtf(var);

    const int i = blockIdx.x * blockDim.x + threadIdx.x;   // exactly NTOT/4 threads
    float4* o4 = (float4*)out;
    float4 v = o4[i];
    v.x = (v.x - mean) * inv;
    v.y = (v.y - mean) * inv;
    v.z = (v.z - mean) * inv;
    v.w = (v.w - mean) * inv;
    o4[i] = v;
}

extern "C" void kernel_launch(void* const* d_in, const int* in_sizes, int n_in,
                              void* d_out, int out_size, void* d_ws, size_t ws_size,
                              hipStream_t stream)
{
    (void)in_sizes; (void)n_in; (void)out_size; (void)ws_size;
    const float* x = (const float*)d_in[0];
    const int*   p = (const int*)d_in[1];
    float* out = (float*)d_out;
    float* ws  = (float*)d_ws;

    dim3 grid(BB, 2);
    gru_fused<<<grid, 512, 0, stream>>>(
        x, p,
        (const float*)d_in[2],  (const float*)d_in[3],
        (const float*)d_in[4],  (const float*)d_in[5],
        (const float*)d_in[6],  (const float*)d_in[7],
        (const float*)d_in[8],  (const float*)d_in[9],
        (const float*)d_in[10], (const float*)d_in[11],
        (const float*)d_in[12], (const float*)d_in[13],
        (const float*)d_in[14], (const float*)d_in[15],
        (const float*)d_in[16], (const float*)d_in[17],
        (const float*)d_in[18], (const float*)d_in[19],
        (const float*)d_in[20], (const float*)d_in[21],
        out, ws);

    normalize_k<<<NTOT / 4 / 256, 256, 0, stream>>>(out, ws);
}

// Round 9
// 184.178 us; speedup vs baseline: 1.0491x; 1.0491x over previous
//
#include <hip/hip_runtime.h>

#define BB 256
#define LL 2048
#define HH 64
#define TT 64            // chunk length along L
#define SS 68            // padded LDS row stride (floats)
#define NCH (LL / TT)    // 32 chunks
#define NTOT (BB * LL * 2)

typedef __attribute__((ext_vector_type(8))) short bf16x8;
typedef __attribute__((ext_vector_type(4))) float f32x4;

__device__ __forceinline__ float rcp_(float x)  { return __builtin_amdgcn_rcpf(x); }

// RNE fp32->bf16 (weights only, outside hot loop)
__device__ __forceinline__ short f2bf_rne(float f) {
    union { float f; unsigned u; } v; v.f = f;
    unsigned r = v.u + 0x7fff + ((v.u >> 16) & 1);
    return (short)(r >> 16);
}

// pack hi16(f_hi):hi16(f_lo) into one dword with a single v_perm_b32
__device__ __forceinline__ unsigned perm_hi16(float f_hi, float f_lo) {
    union { float f; unsigned u; } a, b;
    a.f = f_hi; b.f = f_lo;
    return __builtin_amdgcn_perm(a.u, b.u, 0x07060302u);
}

// DPP row_shr:D with zero bound: lane i receives lane i-D within its 16-lane row.
template<int D>
__device__ __forceinline__ float rshr(float x) {
    union { float f; int i; } u, r;
    u.f = x;
    r.i = __builtin_amdgcn_update_dpp(0, u.i, 0x110 | D, 0xF, 0xF, true);
    return r.f;
}

// broadcast lane (group8 | 7) within each 8-lane group: ds_swizzle bit-mode,
// src = (lane & 0x18) | 7 within each 32-lane half (bit 5 preserved by HW).
// Register-neutral replacement for __shfl(x, lane|7); HW-verified in r8.
__device__ __forceinline__ float bcast7(float x) {
    union { float f; int i; } u, r;
    u.f = x;
    r.i = __builtin_amdgcn_ds_swizzle(u.i, 0x00F8);
    return r.f;
}

// Layer-0 gates (Bernoulli bit-LUT) + 64-step chunk scan split over 8 waves:
// each lane owns 8 local steps (seg = lane&7); guarded row_shr DPP scan over
// segments. Gates recomputed from packed bits in the apply loop (r5 form —
// the r8 ai/bi cache added 16 VGPRs of live range across the DPP scan and
// spilled ~38MB of scratch traffic; see FETCH/WRITE blowup in r8 counters).
__device__ __forceinline__ void p1_scan(const unsigned* __restrict__ bw, int c,
                                        float a0v, float b0v, float a1v, float b1v,
                                        int seg, int col0,
                                        float& carry, float* sh)
{
    const unsigned bits = (bw[c * 2 + (seg >> 2)] >> ((seg & 3) << 3)) & 0xffu;
    float A = 1.0f, Bv = 0.0f;
    #pragma unroll
    for (int i = 0; i < 8; ++i) {
        const bool on = (bits >> i) & 1u;
        const float a = on ? a1v : a0v;
        const float b = on ? b1v : b0v;
        A  = A * a;
        Bv = fmaf(Bv, a, b);
    }
    // inclusive Hillis-Steele over 8 segments (strides 1,2,4)
    {
        const float Au = rshr<1>(A), Bu = rshr<1>(Bv);
        if (seg >= 1) { const float Ac = A; A = Au * Ac; Bv = fmaf(Bu, Ac, Bv); }
    }
    {
        const float Au = rshr<2>(A), Bu = rshr<2>(Bv);
        if (seg >= 2) { const float Ac = A; A = Au * Ac; Bv = fmaf(Bu, Ac, Bv); }
    }
    {
        const float Au = rshr<4>(A), Bu = rshr<4>(Bv);
        if (seg >= 4) { const float Ac = A; A = Au * Ac; Bv = fmaf(Bu, Ac, Bv); }
    }
    // exclusive transform for this segment's incoming state
    float Ae = rshr<1>(A), Be = rshr<1>(Bv);
    if (seg == 0) { Ae = 1.0f; Be = 0.0f; }
    float cc = fmaf(Ae, carry, Be);
    #pragma unroll
    for (int i = 0; i < 8; ++i) {
        const bool on = (bits >> i) & 1u;
        const float a = on ? a1v : a0v;
        const float b = on ? b1v : b0v;
        cc = fmaf(a, cc, b);
        sh[(seg * 8 + i) * SS + col0] = cc;
    }
    carry = bcast7(cc);   // seg==7 lane of this h-group holds chunk-final state
}

// 8 waves = 4 t-waves x 2 h-halves (in-block H-split) — exact r5 skeleton and
// phase order (G2 -> G1 -> P1 -> barrier; loads inside G1). Only the two
// register-neutral r8 items kept: bcast7 and readfirstlane-uniform wave ids
// (SGPR-izes tw/hw-derived addressing, freeing VGPRs). The r8 L[4] hoist and
// phase reorder added cross-phase liveness at the 128-reg knife edge -> spill.
__global__ void __launch_bounds__(512)
__attribute__((amdgpu_waves_per_eu(4, 4)))
gru_fused(const float* __restrict__ x, const int* __restrict__ p,
               const float* __restrict__ w1z0, const float* __restrict__ b1z0,
               const float* __restrict__ w1h0, const float* __restrict__ b1h0,
               const float* __restrict__ w1z1, const float* __restrict__ b1z1,
               const float* __restrict__ w1h1, const float* __restrict__ b1h1,
               const float* __restrict__ w1o,  const float* __restrict__ b1o,
               const float* __restrict__ w2z0, const float* __restrict__ b2z0,
               const float* __restrict__ w2h0, const float* __restrict__ b2h0,
               const float* __restrict__ w2z1, const float* __restrict__ b2z1,
               const float* __restrict__ w2h1, const float* __restrict__ b2h1,
               const float* __restrict__ w2o,  const float* __restrict__ b2o,
               float* __restrict__ out, float* __restrict__ ws)
{
    const int  b  = blockIdx.x;
    const bool pm = (blockIdx.y != 0);

    const float* wz0 = pm ? w2z0 : w1z0;
    const float* bz0 = pm ? b2z0 : b1z0;
    const float* wh0 = pm ? w2h0 : w1h0;
    const float* bh0 = pm ? b2h0 : b1h0;
    const float* wz1 = pm ? w2z1 : w1z1;
    const float* bz1 = pm ? b2z1 : b1z1;
    const float* wh1 = pm ? w2h1 : w1h1;
    const float* bh1 = pm ? b2h1 : b1h1;
    const float* wo  = pm ? w2o  : w1o;
    const float* bov = pm ? b2o  : b1o;

    const int tid   = threadIdx.x;
    const int lane  = tid & 63;
    const int tg    = tid >> 6;          // wave id (8)
    const int tgu   = __builtin_amdgcn_readfirstlane(tg);   // provably uniform
    const int twu   = tgu & 3;           // t sub-block wave (uniform)
    const int hwu   = tgu >> 2;          // h-half (uniform)
    const int q     = lane >> 4;         // MFMA quad (t sub-block)
    const int n     = lane & 15;         // MFMA col (h low bits)
    const int seg   = lane & 7;          // P1 segment (8 per h)
    const int hidx  = (tgu << 3) | (lane >> 3);   // P1 h channel (0..63)

    __shared__ __align__(16) float s_h[2 * TT * SS];   // double-buffered h0 (34.8 KB)
    __shared__ unsigned long long s_xb[LL / 64];       // bit-packed (permuted) x row
    __shared__ float2 s_w[2][2][4][32];                // [buf][hw][tw][ht*16+n]
    __shared__ float s_o[2][4][16];                    // [buf][tw][q*4+r] hw1 partials
    __shared__ float s_red[16];

    const float* xrow = x + (size_t)b * LL;

    // ---- stage x row as BITS (ballot-packed; pm branch gathers once here) ----
    #pragma unroll
    for (int g = 0; g < 4; ++g) {
        const int idx = g * 512 + tid;
        const int src = pm ? p[idx] : idx;
        const unsigned long long m = __ballot(xrow[src] != 0.0f);
        if (lane == 0) s_xb[g * 8 + tgu] = m;
    }
    const unsigned* bw = (const unsigned*)s_xb;

    // ---- layer-0 LUT per hidx (x is bernoulli {0,1}) ----
    const float z0v = rcp_(1.0f + __expf(-bz0[hidx]));
    const float z1v = rcp_(1.0f + __expf(-(wz0[hidx] + bz0[hidx])));
    const float a0v = 1.0f - z0v, b0v = z0v * bh0[hidx];
    const float a1v = 1.0f - z1v, b1v = z1v * (wh0[hidx] + bh0[hidx]);

    // ---- layer-1 biases + output weights for THIS h-half ----
    float rbz1[2], rbh1[2], rwo4[2];
    #pragma unroll
    for (int ht = 0; ht < 2; ++ht) {
        const int h = hwu * 32 + ht * 16 + n;
        rbz1[ht] = bz1[h];
        rbh1[ht] = bh1[h];
        rwo4[ht] = wo[h];
    }
    const float bo = bov[0];   // added once, by hw0 at combine time

    // ---- layer-1 weight B-fragments (this half), RNE hi only ----
    bf16x8 wfz[2][2], wfh[2][2];
    for (int ks = 0; ks < 2; ++ks) {
        for (int ht = 0; ht < 2; ++ht) {
            #pragma unroll
            for (int j = 0; j < 8; ++j) {
                const int kk = ks * 32 + q * 8 + j;
                const int h  = hwu * 32 + ht * 16 + n;
                wfz[ks][ht][j] = f2bf_rne(wz1[kk * HH + h]);
                wfh[ks][ht][j] = f2bf_rne(wh1[kk * HH + h]);
            }
        }
    }

    float carry0 = 0.0f;
    float carry1[2] = {0.0f, 0.0f};    // per ht (h = hw*32 + ht*16 + n)
    f32x4 ga[2], gb[2];                // layer-1 gates (a,b), chunk-persistent
    float Aqe[2], Bqe[2];              // exclusive-q transforms, chunk-persistent
    float pvo[4] = {0, 0, 0, 0};       // hw0's deferred projection partials
    float lsum = 0.0f, lsum2 = 0.0f;
    float* outp = out + (pm ? 1 : 0);
    const int t0 = twu * 16;
    const int col0 = hidx ^ (seg << 2);           // s_h col swizzle (write side)
    const int sswz = (twu * 2 + (n >> 3)) << 2;   // read-side un-swizzle

    // G2: deferred combine of chunk cm-1 (hw1's partial arrived via s_o, synced),
    // then apply layer-1 scan for chunk cm + half projection.
    auto g2_step = [&](int cm) {
        if (cm > 0 && hwu == 0 && n == 15) {
            #pragma unroll
            for (int r = 0; r < 4; ++r) {
                const float v = pvo[r] + s_o[(cm - 1) & 1][twu][q * 4 + r] + bo;
                outp[((size_t)b * LL + (cm - 1) * TT + t0 + q * 4 + r) * 2] = v;
                lsum += v;
                lsum2 = fmaf(v, v, lsum2);
            }
        }
        const int buf = cm & 1;
        float Acm[2] = {1, 1}, Bcm[2] = {0, 0};
        float Ap[2], Bp[2];
        #pragma unroll
        for (int w = 0; w < 4; ++w) {
            #pragma unroll
            for (int ht = 0; ht < 2; ++ht) {
                if (w == twu) { Ap[ht] = Acm[ht]; Bp[ht] = Bcm[ht]; }  // uniform branch
                const float2 ab = s_w[buf][hwu][w][ht * 16 + n];
                Bcm[ht] = fmaf(ab.x, Bcm[ht], ab.y);
                Acm[ht] *= ab.x;
            }
        }
        float vo[4] = {0, 0, 0, 0};
        #pragma unroll
        for (int ht = 0; ht < 2; ++ht) {
            float cc = fmaf(Aqe[ht], fmaf(Ap[ht], carry1[ht], Bp[ht]), Bqe[ht]);
            #pragma unroll
            for (int r = 0; r < 4; ++r) {
                cc = fmaf(ga[ht][r], cc, gb[ht][r]);
                vo[r] = fmaf(cc, rwo4[ht], vo[r]);
            }
            carry1[ht] = fmaf(Acm[ht], carry1[ht], Bcm[ht]);
        }
        // shift-reduce over n (16-lane rows): lane n==15 gets the half-sum
        #pragma unroll
        for (int r = 0; r < 4; ++r) {
            vo[r] += rshr<1>(vo[r]);
            vo[r] += rshr<2>(vo[r]);
            vo[r] += rshr<4>(vo[r]);
            vo[r] += rshr<8>(vo[r]);
        }
        if (n == 15) {
            if (hwu) {
                #pragma unroll
                for (int r = 0; r < 4; ++r) s_o[buf][twu][q * 4 + r] = vo[r];
            } else {
                #pragma unroll
                for (int r = 0; r < 4; ++r) pvo[r] = vo[r];
            }
        }
    };

    __syncthreads();   // s_xb staged

    // ---- prologue: P1(0) -> s_h buf 0 ----
    p1_scan(bw, 0, a0v, b0v, a1v, b1v, seg, col0, carry0, s_h);
    __syncthreads();

    for (int c = 0; c < NCH; ++c) {
        const int cp1 = c + 1;

        // ---- G2(c-1): uses previous chunk's gates (still in registers) ----
        if (c > 0) g2_step(c - 1);

        // ---- G1(c): MFMA + gates + per-wave scan transforms (this h-half) ----
        {
            #pragma unroll
            for (int ht = 0; ht < 2; ++ht) {
                ga[ht] = (f32x4){rbz1[ht], rbz1[ht], rbz1[ht], rbz1[ht]};
                gb[ht] = (f32x4){rbh1[ht], rbh1[ht], rbh1[ht], rbh1[ht]};
            }
            const float* shR = s_h + (c & 1) * (TT * SS);
            #pragma unroll
            for (int ks = 0; ks < 2; ++ks) {
                const int base = ks * 32 + q * 8;
                const float* rowp = &shR[(t0 + n) * SS];
                const float4 av0 = *(const float4*)(rowp + (base ^ sswz));
                const float4 av1 = *(const float4*)(rowp + ((base + 4) ^ sswz));
                float af[8] = {av0.x, av0.y, av0.z, av0.w, av1.x, av1.y, av1.z, av1.w};
                // hi16 pack via v_perm; exact remainder -> lo bf16
                union { bf16x8 v; unsigned d[4]; } ahi, alo;
                float rem[8];
                #pragma unroll
                for (int j = 0; j < 8; ++j) {
                    union { float f; unsigned u; } uf; uf.f = af[j];
                    union { unsigned u; float f; } hf; hf.u = uf.u & 0xffff0000u;
                    rem[j] = af[j] - hf.f;                     // exact
                }
                #pragma unroll
                for (int k = 0; k < 4; ++k) {
                    ahi.d[k] = perm_hi16(af[2 * k + 1], af[2 * k]);
                    alo.d[k] = perm_hi16(rem[2 * k + 1], rem[2 * k]);
                }
                #pragma unroll
                for (int ht = 0; ht < 2; ++ht) {
                    ga[ht] = __builtin_amdgcn_mfma_f32_16x16x32_bf16(ahi.v, wfz[ks][ht], ga[ht], 0, 0, 0);
                    ga[ht] = __builtin_amdgcn_mfma_f32_16x16x32_bf16(alo.v, wfz[ks][ht], ga[ht], 0, 0, 0);
                    gb[ht] = __builtin_amdgcn_mfma_f32_16x16x32_bf16(ahi.v, wfh[ks][ht], gb[ht], 0, 0, 0);
                    gb[ht] = __builtin_amdgcn_mfma_f32_16x16x32_bf16(alo.v, wfh[ks][ht], gb[ht], 0, 0, 0);
                }
            }
            // gates in place: a = 1-sigmoid(v) = rcp(1+exp(v)); b = htl - a*htl
            #pragma unroll
            for (int ht = 0; ht < 2; ++ht) {
                #pragma unroll
                for (int r = 0; r < 4; ++r) {
                    const float v   = ga[ht][r];
                    const float a   = rcp_(1.0f + __expf(v));
                    const float htl = gb[ht][r];
                    ga[ht][r] = a;
                    gb[ht][r] = fmaf(-a, htl, htl);
                }
            }
            // compose own 4 r-steps per ht
            float Aq[2], Bq[2];
            #pragma unroll
            for (int ht = 0; ht < 2; ++ht) {
                float A = 1.0f, B = 0.0f;
                #pragma unroll
                for (int r = 0; r < 4; ++r) {
                    B = fmaf(ga[ht][r], B, gb[ht][r]);
                    A = A * ga[ht][r];
                }
                Aq[ht] = A; Bq[ht] = B;
            }
            // inclusive Hillis-Steele over q (strides 16, 32 lanes)
            #pragma unroll
            for (int ht = 0; ht < 2; ++ht) {
                const float Au = __shfl_up(Aq[ht], 16), Bu = __shfl_up(Bq[ht], 16);
                if (q >= 1) { const float Ac = Aq[ht]; Aq[ht] = Ac * Au; Bq[ht] = fmaf(Ac, Bu, Bq[ht]); }
            }
            #pragma unroll
            for (int ht = 0; ht < 2; ++ht) {
                const float Au = __shfl_up(Aq[ht], 32), Bu = __shfl_up(Bq[ht], 32);
                if (q >= 2) { const float Ac = Aq[ht]; Aq[ht] = Ac * Au; Bq[ht] = fmaf(Ac, Bu, Bq[ht]); }
            }
            // exclusive-q transforms (persist to G2)
            #pragma unroll
            for (int ht = 0; ht < 2; ++ht) {
                const float Ae = __shfl_up(Aq[ht], 16), Be = __shfl_up(Bq[ht], 16);
                Aqe[ht] = (q == 0) ? 1.0f : Ae;
                Bqe[ht] = (q == 0) ? 0.0f : Be;
            }
            // q==3 lanes publish the wave-block inclusive transform
            if (q == 3) {
                #pragma unroll
                for (int ht = 0; ht < 2; ++ht)
                    s_w[c & 1][hwu][twu][ht * 16 + n] = make_float2(Aq[ht], Bq[ht]);
            }
        }

        // ---- P1(c+1) -> other s_h buffer (reads bit-packed x) ----
        if (cp1 < NCH)
            p1_scan(bw, cp1, a0v, b0v, a1v, b1v, seg, col0, carry0,
                    s_h + (cp1 & 1) * (TT * SS));

        __syncthreads();
    }

    // ---- G2 for the last chunk, then final deferred combine ----
    g2_step(NCH - 1);
    __syncthreads();
    if (hwu == 0 && n == 15) {
        #pragma unroll
        for (int r = 0; r < 4; ++r) {
            const float v = pvo[r] + s_o[(NCH - 1) & 1][twu][q * 4 + r] + bo;
            outp[((size_t)b * LL + (NCH - 1) * TT + t0 + q * 4 + r) * 2] = v;
            lsum += v;
            lsum2 = fmaf(v, v, lsum2);
        }
    }

    // ---- block partial (sum, sumsq) -> ws slots (plain stores) ----
    #pragma unroll
    for (int o = 32; o; o >>= 1) {
        lsum  += __shfl_down(lsum, o);
        lsum2 += __shfl_down(lsum2, o);
    }
    if (lane == 0) { s_red[tgu] = lsum; s_red[8 + tgu] = lsum2; }
    __syncthreads();
    if (tid == 0) {
        float s = 0.0f, s2 = 0.0f;
        #pragma unroll
        for (int i = 0; i < 8; ++i) { s += s_red[i]; s2 += s_red[8 + i]; }
        const int gb2 = b * 2 + (pm ? 1 : 0);
        ws[2 * gb2]     = s;
        ws[2 * gb2 + 1] = s2;
    }
}

// Fold the 512 block-partials (redundantly per block), normalize in-place.
__global__ void normalize_k(float* __restrict__ out, const float* __restrict__ ws)
{
    __shared__ float s_red[8];
    float s = 0.0f, s2 = 0.0f;
    for (int i = threadIdx.x; i < 2 * BB; i += 256) {
        s  += ws[2 * i];
        s2 += ws[2 * i + 1];
    }
    #pragma unroll
    for (int o = 32; o; o >>= 1) {
        s  += __shfl_down(s, o);
        s2 += __shfl_down(s2, o);
    }
    const int wid = threadIdx.x >> 6;
    if ((threadIdx.x & 63) == 0) { s_red[wid] = s; s_red[4 + wid] = s2; }
    __syncthreads();
    const float tot  = s_red[0] + s_red[1] + s_red[2] + s_red[3];
    const float tot2 = s_red[4] + s_red[5] + s_red[6] + s_red[7];
    const float N    = (float)NTOT;
    const float mean = tot / N;
    const float var  = (tot2 - N * mean * mean) / (N - 1.0f);
    const float inv  = rsqrtf(var);

    const int i = blockIdx.x * blockDim.x + threadIdx.x;   // exactly NTOT/4 threads
    float4* o4 = (float4*)out;
    float4 v = o4[i];
    v.x = (v.x - mean) * inv;
    v.y = (v.y - mean) * inv;
    v.z = (v.z - mean) * inv;
    v.w = (v.w - mean) * inv;
    o4[i] = v;
}

extern "C" void kernel_launch(void* const* d_in, const int* in_sizes, int n_in,
                              void* d_out, int out_size, void* d_ws, size_t ws_size,
                              hipStream_t stream)
{
    (void)in_sizes; (void)n_in; (void)out_size; (void)ws_size;
    const float* x = (const float*)d_in[0];
    const int*   p = (const int*)d_in[1];
    float* out = (float*)d_out;
    float* ws  = (float*)d_ws;

    dim3 grid(BB, 2);
    gru_fused<<<grid, 512, 0, stream>>>(
        x, p,
        (const float*)d_in[2],  (const float*)d_in[3],
        (const float*)d_in[4],  (const float*)d_in[5],
        (const float*)d_in[6],  (const float*)d_in[7],
        (const float*)d_in[8],  (const float*)d_in[9],
        (const float*)d_in[10], (const float*)d_in[11],
        (const float*)d_in[12], (const float*)d_in[13],
        (const float*)d_in[14], (const float*)d_in[15],
        (const float*)d_in[16], (const float*)d_in[17],
        (const float*)d_in[18], (const float*)d_in[19],
        (const float*)d_in[20], (const float*)d_in[21],
        out, ws);

    normalize_k<<<NTOT / 4 / 256, 256, 0, stream>>>(out, ws);
}